// Round 1
// baseline (7621.841 us; speedup 1.0000x reference)
//
#include <hip/hip_runtime.h>
#include <math.h>

#define HID 256
#define EBUY 200000
#define NNODE 30000
static const size_t S = (size_t)NNODE * HID;   // 7,680,000 floats per node-feature tensor

__device__ __forceinline__ float gelu_f(float x) {
    return 0.5f * x * (1.0f + erff(x * 0.70710678118654752f));
}
__device__ __forceinline__ unsigned flipf(float f) {
    unsigned u = __float_as_uint(f);
    return (u & 0x80000000u) ? ~u : (u | 0x80000000u);
}
__device__ __forceinline__ float unflipf(unsigned u) {
    return __uint_as_float((u & 0x80000000u) ? (u & 0x7FFFFFFFu) : ~u);
}

// ---------------- GEMM: C[M,N] = op(A)[M,K] @ B[K,N] + bias ----------------
// EPI 0: D0[r*N+c] = v
// EPI 1: split into 256-col chunks -> D0, D1, D2
// EPI 2: skip-gate + residual: D0[r*256+c] = sg*v + (2-sg)*resid[r*256+c]
// GELU_A: apply exact gelu to A elements while staging into LDS.
template<int GELU_A, int EPI>
__launch_bounds__(256)
__global__ void gemm64(const float* __restrict__ A, const float* __restrict__ B,
                       const float* __restrict__ bias,
                       float* __restrict__ D0, float* __restrict__ D1, float* __restrict__ D2,
                       int M, int N, int K,
                       const int* __restrict__ gatherA,
                       const float* __restrict__ skipP, const float* __restrict__ resid)
{
    __shared__ float As[16][68];
    __shared__ float Bs[16][68];
    const int row0 = blockIdx.y * 64;
    const int col0 = blockIdx.x * 64;
    const int tid = threadIdx.x;
    const int tx = tid & 15, ty = tid >> 4;
    float acc[4][4] = {};

    for (int k0 = 0; k0 < K; k0 += 16) {
        #pragma unroll
        for (int i = 0; i < 4; ++i) {          // A tile: 64 rows x 16 k
            int e = tid + i * 256;
            int r = e >> 4, kk = e & 15;
            int gr = row0 + r;
            float v = 0.f;
            if (gr < M && (k0 + kk) < K) {
                int ar = gatherA ? gatherA[gr] : gr;
                v = A[(size_t)ar * K + k0 + kk];
            }
            if (GELU_A) v = gelu_f(v);
            As[kk][r] = v;
        }
        #pragma unroll
        for (int i = 0; i < 4; ++i) {          // B tile: 16 k x 64 cols
            int e = tid + i * 256;
            int kk = e >> 6, c = e & 63;
            float v = 0.f;
            if ((k0 + kk) < K && (col0 + c) < N)
                v = B[(size_t)(k0 + kk) * N + col0 + c];
            Bs[kk][c] = v;
        }
        __syncthreads();
        #pragma unroll
        for (int kk = 0; kk < 16; ++kk) {
            float4 a4 = *(const float4*)&As[kk][ty * 4];
            float4 b4 = *(const float4*)&Bs[kk][tx * 4];
            float a[4] = {a4.x, a4.y, a4.z, a4.w};
            float b[4] = {b4.x, b4.y, b4.z, b4.w};
            #pragma unroll
            for (int i = 0; i < 4; ++i)
                #pragma unroll
                for (int j = 0; j < 4; ++j)
                    acc[i][j] += a[i] * b[j];
        }
        __syncthreads();
    }

    float sg = 0.f;
    if (EPI == 2) sg = 1.f / (1.f + expf(-skipP[0]));
    #pragma unroll
    for (int i = 0; i < 4; ++i) {
        int r = row0 + ty * 4 + i;
        if (r >= M) continue;
        #pragma unroll
        for (int j = 0; j < 4; ++j) {
            int c = col0 + tx * 4 + j;
            if (c >= N) continue;
            float v = acc[i][j] + (bias ? bias[c] : 0.f);
            if (EPI == 0) {
                D0[(size_t)r * N + c] = v;
            } else if (EPI == 1) {
                float* D = (c < 256) ? D0 : ((c < 512) ? D1 : D2);
                D[(size_t)r * 256 + (c & 255)] = v;
            } else {
                float x = resid[(size_t)r * 256 + c];
                D0[(size_t)r * 256 + c] = sg * v + (2.f - sg) * x;
            }
        }
    }
}

// ------------- fuse k_rel/v_rel into kqv weights -------------
// Wf cols: includeQ: [0,256)=k@R, [256,512)=q copy, [512,768)=v@R ; else [0,256)=k@R,[256,512)=v@R
__global__ void build_fused(const float* __restrict__ W,    // [256,768] slice of kqv_W
                            const float* __restrict__ bvec, // [768] slice of kqv_b
                            const float* __restrict__ kR,   // [4,64,64] slice of k_rel
                            const float* __restrict__ vR,
                            float* __restrict__ Wf, float* __restrict__ bf,
                            int includeQ)
{
    int ncols = includeQ ? 768 : 512;
    int tid = blockIdx.x * 256 + threadIdx.x;
    int total = 257 * ncols;
    if (tid >= total) return;
    int r = tid / ncols, c = tid % ncols;
    int cb = c >> 8, cc = c & 255;
    int h = cc >> 6, dd = cc & 63;
    const float* Wrow = (r < 256) ? (W + (size_t)r * 768) : bvec;
    float out;
    if (includeQ && cb == 1) {
        out = Wrow[256 + cc];
    } else {
        const float* R = ((cb == 0) ? kR : vR) + (size_t)h * 64 * 64;
        int srcbase = (cb == 0) ? 0 : 512;
        float s = 0.f;
        #pragma unroll 8
        for (int d = 0; d < 64; ++d)
            s += Wrow[srcbase + h * 64 + d] * R[d * 64 + dd];
        out = s;
    }
    if (r < 256) Wf[(size_t)r * ncols + c] = out;
    else bf[c] = out;
}

// ------------- logits -------------
// assoc edges (si = di = node index), dst = item. 16 lanes per (node, head) dot.
__global__ void logit_assoc(const float* __restrict__ q1, const float* __restrict__ ke,
                            const float* __restrict__ pRel,
                            float* __restrict__ logits, unsigned* __restrict__ mDst)
{
    int g = blockIdx.x * 256 + threadIdx.x;
    int grp = g >> 4, lane = g & 15;
    if (grp >= NNODE * 4) return;
    int n = grp >> 2, h = grp & 3;
    float4 qv = *(const float4*)(q1 + (size_t)n * 256 + h * 64 + lane * 4);
    float4 kv = *(const float4*)(ke + (size_t)n * 256 + h * 64 + lane * 4);
    float d = qv.x * kv.x + qv.y * kv.y + qv.z * kv.z + qv.w * kv.w;
    for (int off = 8; off; off >>= 1) d += __shfl_xor(d, off, 16);
    if (lane == 0) {
        float lg = d * pRel[h] * 0.125f;
        logits[grp] = lg;
        atomicMax(&mDst[grp], flipf(lg));
    }
}

__global__ void logit_buys(const float* __restrict__ qd, const float* __restrict__ ke,
                           const int* __restrict__ srcIdx, const int* __restrict__ dstIdx,
                           const float* __restrict__ pRel,
                           float* __restrict__ logits, unsigned* __restrict__ mDst, int E)
{
    int g = blockIdx.x * 256 + threadIdx.x;
    int grp = g >> 4, lane = g & 15;
    if (grp >= E * 4) return;
    int j = grp >> 2, h = grp & 3;
    int si = srcIdx[j], di = dstIdx[j];
    float4 qv = *(const float4*)(qd + (size_t)di * 256 + h * 64 + lane * 4);
    float4 kv = *(const float4*)(ke + (size_t)si * 256 + h * 64 + lane * 4);
    float d = qv.x * kv.x + qv.y * kv.y + qv.z * kv.z + qv.w * kv.w;
    for (int off = 8; off; off >>= 1) d += __shfl_xor(d, off, 16);
    if (lane == 0) {
        float lg = d * pRel[h] * 0.125f;
        logits[grp] = lg;
        atomicMax(&mDst[(size_t)di * 4 + h], flipf(lg));
    }
}

// e = exp(logit - m[dst]); store back; s[dst] += e
__global__ void sumexp(float* __restrict__ logits, const unsigned* __restrict__ m,
                       float* __restrict__ s, const int* __restrict__ dstIdx, int E)
{
    int g = blockIdx.x * 256 + threadIdx.x;
    if (g >= E * 4) return;
    int j = g >> 2, h = g & 3;
    int d = dstIdx ? dstIdx[j] : j;
    float e = expf(logits[g] - unflipf(m[(size_t)d * 4 + h]));
    logits[g] = e;
    atomicAdd(&s[(size_t)d * 4 + h], e);
}

// agg[dst] += (e / (s+1e-16)) * ve[src]
__global__ void scatter_msgs(const float* __restrict__ logits, const float* __restrict__ s,
                             const float* __restrict__ ve,
                             const int* __restrict__ srcIdx, const int* __restrict__ dstIdx,
                             float* __restrict__ agg, int E)
{
    int g = blockIdx.x * 256 + threadIdx.x;
    int grp = g >> 4, lane = g & 15;
    if (grp >= E * 4) return;
    int j = grp >> 2, h = grp & 3;
    int si = srcIdx ? srcIdx[j] : j;
    int di = dstIdx ? dstIdx[j] : j;
    float alpha = logits[grp] / (s[(size_t)di * 4 + h] + 1e-16f);
    float4 vv = *(const float4*)(ve + (size_t)si * 256 + h * 64 + lane * 4);
    float* dp = agg + (size_t)di * 256 + h * 64 + lane * 4;
    atomicAdd(dp + 0, alpha * vv.x);
    atomicAdd(dp + 1, alpha * vv.y);
    atomicAdd(dp + 2, alpha * vv.z);
    atomicAdd(dp + 3, alpha * vv.w);
}

// ------------- batch-norm -------------
__global__ void bn_stats(const float* __restrict__ x, float* __restrict__ sums, int M)
{
    int col = threadIdx.x;
    int rpb = (M + gridDim.x - 1) / gridDim.x;
    int r0 = blockIdx.x * rpb, r1 = min(M, r0 + rpb);
    float s = 0.f, s2 = 0.f;
    for (int r = r0; r < r1; ++r) {
        float v = x[(size_t)r * 256 + col];
        s += v; s2 += v * v;
    }
    atomicAdd(&sums[col], s);
    atomicAdd(&sums[256 + col], s2);
}

__global__ void bn_apply(const float* __restrict__ x, const float* __restrict__ sums,
                         const float* __restrict__ g, const float* __restrict__ b,
                         float* __restrict__ y, int M)
{
    size_t total = (size_t)M * 256;
    int col = threadIdx.x & 255;
    float mu = sums[col] / (float)M;
    float var = sums[256 + col] / (float)M - mu * mu;
    float sc = rsqrtf(var + 1e-5f) * g[col];
    float sh = b[col];
    for (size_t i = (size_t)blockIdx.x * 256 + threadIdx.x; i < total; i += (size_t)gridDim.x * 256) {
        float v = (x[i] - mu) * sc + sh;
        y[i] = fmaxf(v, 0.f);
    }
}

// ---------------- host orchestration ----------------
static inline void launch_gemm(const float* A, const float* B, const float* bias,
                               float* D0, float* D1, float* D2,
                               int M, int N, int K, const int* gather,
                               int gelu, int epi, const float* skipP, const float* resid,
                               hipStream_t stream)
{
    dim3 grid((N + 63) / 64, (M + 63) / 64);
    dim3 blk(256);
    if (gelu == 0 && epi == 0)
        hipLaunchKernelGGL((gemm64<0, 0>), grid, blk, 0, stream, A, B, bias, D0, D1, D2, M, N, K, gather, skipP, resid);
    else if (gelu == 0 && epi == 1)
        hipLaunchKernelGGL((gemm64<0, 1>), grid, blk, 0, stream, A, B, bias, D0, D1, D2, M, N, K, gather, skipP, resid);
    else
        hipLaunchKernelGGL((gemm64<1, 2>), grid, blk, 0, stream, A, B, bias, D0, D1, D2, M, N, K, gather, skipP, resid);
}

extern "C" void kernel_launch(void* const* d_in, const int* in_sizes, int n_in,
                              void* d_out, int out_size, void* d_ws, size_t ws_size,
                              hipStream_t stream)
{
    const int*   user_id    = (const int*)d_in[0];
    const int*   item_id    = (const int*)d_in[1];
    const int*   buys_src   = (const int*)d_in[2];
    const int*   buys_dst   = (const int*)d_in[3];
    const float* image_feat = (const float*)d_in[4];
    const float* taste_feat = (const float*)d_in[5];
    const float* intent_feat= (const float*)d_in[6];
    const float* user_emb   = (const float*)d_in[7];
    const float* user_W     = (const float*)d_in[8];
    const float* user_b     = (const float*)d_in[9];
    const float* user_bn_g  = (const float*)d_in[10];
    const float* user_bn_b  = (const float*)d_in[11];
    const float* item_emb   = (const float*)d_in[12];
    const float* item_W     = (const float*)d_in[13];
    const float* item_b     = (const float*)d_in[14];
    const float* item_bn_g  = (const float*)d_in[15];
    const float* item_bn_b  = (const float*)d_in[16];
    const float* img_U      = (const float*)d_in[17];
    const float* img_V      = (const float*)d_in[18];
    const float* img_b      = (const float*)d_in[19];
    const float* taste_W    = (const float*)d_in[20];
    const float* taste_b    = (const float*)d_in[21];
    const float* intent_W   = (const float*)d_in[22];
    const float* intent_b   = (const float*)d_in[23];
    const float* kqv_W      = (const float*)d_in[24];
    const float* kqv_b      = (const float*)d_in[25];
    const float* out_W      = (const float*)d_in[26];
    const float* out_b      = (const float*)d_in[27];
    const float* k_rel      = (const float*)d_in[28];
    const float* v_rel      = (const float*)d_in[29];
    const float* p_rel      = (const float*)d_in[30];
    const float* skip       = (const float*)d_in[31];
    const float* fbn_g      = (const float*)d_in[32];
    const float* fbn_b      = (const float*)d_in[33];

    float* out = (float*)d_out;
    float* ws  = (float*)d_ws;

    float* VE  = ws;             // 5S : relation-transformed v per source type
    float* Q   = ws + 5 * S;     // 2S : q for types 0,1
    float* KE  = ws + 7 * S;     // 2S : relation-transformed k (slot0 reused for t>=2)
    float* AGG = ws + 9 * S;     // 1S
    float* TMP = KE;             // alias: free whenever TMP is used
    float* Wf  = ws + 10 * S;    // 196608
    float* bf  = Wf + 196608;    // 768
    float* LI  = bf + 768;       // item logits: e0,e1,e2 (120000 each) + buys (800000)
    float* LU  = LI + 1160000;   // user logits: 800000
    unsigned* MI = (unsigned*)(LU + 800000);  // 120000
    float*    SI = (float*)(MI + 120000);     // 120000
    unsigned* MU = (unsigned*)(SI + 120000);  // 120000
    float*    SU = (float*)(MU + 120000);     // 120000
    float*    BNS = SU + 120000;              // 512

    size_t need = (size_t)((char*)(BNS + 512) - (char*)ws);
    if (ws_size < need) return;  // workspace too small — fail loudly via wrong output

    float* xs[5] = { out, out + S, out + 2 * S, out + 3 * S, out + 4 * S };
    const int M = NNODE;

    // ---------------- encoders ----------------
    // taste -> xs[2], intent -> xs[3]
    launch_gemm(taste_feat, taste_W, taste_b, xs[2], 0, 0, M, 256, 768, nullptr, 0, 0, 0, 0, stream);
    launch_gemm(intent_feat, intent_W, intent_b, xs[3], 0, 0, M, 256, 20, nullptr, 0, 0, 0, 0, stream);
    // image: low-rank -> xs[4]
    launch_gemm(image_feat, img_U, nullptr, TMP, 0, 0, M, 64, 512, nullptr, 0, 0, 0, 0, stream);
    launch_gemm(TMP, img_V, img_b, xs[4], 0, 0, M, 256, 64, nullptr, 0, 0, 0, 0, stream);
    // user: emb[user_id] @ W + b -> BN -> relu -> xs[0]
    launch_gemm(user_emb, user_W, user_b, TMP, 0, 0, M, 256, 64, user_id, 0, 0, 0, 0, stream);
    hipMemsetAsync(BNS, 0, 512 * 4, stream);
    bn_stats<<<120, 256, 0, stream>>>(TMP, BNS, M);
    bn_apply<<<2048, 256, 0, stream>>>(TMP, BNS, user_bn_g, user_bn_b, xs[0], M);
    // item
    launch_gemm(item_emb, item_W, item_b, TMP, 0, 0, M, 256, 64, item_id, 0, 0, 0, 0, stream);
    hipMemsetAsync(BNS, 0, 512 * 4, stream);
    bn_stats<<<120, 256, 0, stream>>>(TMP, BNS, M);
    bn_apply<<<2048, 256, 0, stream>>>(TMP, BNS, item_bn_g, item_bn_b, xs[1], M);

    // ---------------- layers ----------------
    static const int esrc[5] = {3, 4, 0, 1, 2};  // src type t -> edge index
    for (int l = 0; l < 2; ++l) {
        // t = 0,1 : produce KE[t], Q[t], VE[t]
        for (int t = 0; t < 2; ++t) {
            int e = esrc[t];
            build_fused<<<(257 * 768 + 255) / 256, 256, 0, stream>>>(
                kqv_W + (size_t)(l * 5 + t) * 256 * 768, kqv_b + (size_t)(l * 5 + t) * 768,
                k_rel + (size_t)(l * 5 + e) * 4 * 64 * 64, v_rel + (size_t)(l * 5 + e) * 4 * 64 * 64,
                Wf, bf, 1);
            launch_gemm(xs[t], Wf, bf, KE + t * S, Q + t * S, VE + t * S, M, 768, 256,
                        nullptr, 0, 1, 0, 0, stream);
        }
        hipMemsetAsync(MI, 0, 120000 * 4, stream);
        hipMemsetAsync(SI, 0, 120000 * 4, stream);
        hipMemsetAsync(MU, 0, 120000 * 4, stream);
        hipMemsetAsync(SU, 0, 120000 * 4, stream);
        // buys edges while KE[0], KE[1] are live
        {
            int groups = EBUY * 4;
            int blocks = (groups * 16 + 255) / 256;
            logit_buys<<<blocks, 256, 0, stream>>>(Q + S, KE, buys_src, buys_dst,
                                                   p_rel + (l * 5 + 3) * 4, LI + 360000, MI, EBUY);
            logit_buys<<<blocks, 256, 0, stream>>>(Q, KE + S, buys_dst, buys_src,
                                                   p_rel + (l * 5 + 4) * 4, LU, MU, EBUY);
        }
        // t = 2..4 : KE slot0 reused; logits immediately
        for (int t = 2; t < 5; ++t) {
            int e = esrc[t];  // 0,1,2
            build_fused<<<(257 * 512 + 255) / 256, 256, 0, stream>>>(
                kqv_W + (size_t)(l * 5 + t) * 256 * 768, kqv_b + (size_t)(l * 5 + t) * 768,
                k_rel + (size_t)(l * 5 + e) * 4 * 64 * 64, v_rel + (size_t)(l * 5 + e) * 4 * 64 * 64,
                Wf, bf, 0);
            launch_gemm(xs[t], Wf, bf, KE, VE + t * S, nullptr, M, 512, 256,
                        nullptr, 0, 1, 0, 0, stream);
            int blocks = (NNODE * 4 * 16 + 255) / 256;
            logit_assoc<<<blocks, 256, 0, stream>>>(Q + S, KE, p_rel + (l * 5 + e) * 4,
                                                    LI + e * 120000, MI);
        }
        // sum-exp
        {
            int bA = (NNODE * 4 + 255) / 256, bB = (EBUY * 4 + 255) / 256;
            sumexp<<<bA, 256, 0, stream>>>(LI, MI, SI, nullptr, NNODE);
            sumexp<<<bA, 256, 0, stream>>>(LI + 120000, MI, SI, nullptr, NNODE);
            sumexp<<<bA, 256, 0, stream>>>(LI + 240000, MI, SI, nullptr, NNODE);
            sumexp<<<bB, 256, 0, stream>>>(LI + 360000, MI, SI, buys_dst, EBUY);
            sumexp<<<bB, 256, 0, stream>>>(LU, MU, SU, buys_src, EBUY);
        }
        // dst = item
        hipMemsetAsync(AGG, 0, S * 4, stream);
        {
            int bA = (NNODE * 4 * 16 + 255) / 256, bB = (EBUY * 4 * 16 + 255) / 256;
            scatter_msgs<<<bA, 256, 0, stream>>>(LI, SI, VE + 2 * S, nullptr, nullptr, AGG, NNODE);
            scatter_msgs<<<bA, 256, 0, stream>>>(LI + 120000, SI, VE + 3 * S, nullptr, nullptr, AGG, NNODE);
            scatter_msgs<<<bA, 256, 0, stream>>>(LI + 240000, SI, VE + 4 * S, nullptr, nullptr, AGG, NNODE);
            scatter_msgs<<<bB, 256, 0, stream>>>(LI + 360000, SI, VE, buys_src, buys_dst, AGG, EBUY);
        }
        launch_gemm(AGG, out_W + (size_t)(l * 5 + 1) * 65536, out_b + (l * 5 + 1) * 256,
                    TMP, 0, 0, M, 256, 256, nullptr, 1, 2, skip + (l * 5 + 1), xs[1], stream);
        hipMemsetAsync(BNS, 0, 512 * 4, stream);
        bn_stats<<<120, 256, 0, stream>>>(TMP, BNS, M);
        bn_apply<<<2048, 256, 0, stream>>>(TMP, BNS, fbn_g + (l * 2 + 1) * 256, fbn_b + (l * 2 + 1) * 256, xs[1], M);
        // dst = user
        hipMemsetAsync(AGG, 0, S * 4, stream);
        {
            int bB = (EBUY * 4 * 16 + 255) / 256;
            scatter_msgs<<<bB, 256, 0, stream>>>(LU, SU, VE + S, buys_dst, buys_src, AGG, EBUY);
        }
        launch_gemm(AGG, out_W + (size_t)(l * 5 + 0) * 65536, out_b + (l * 5 + 0) * 256,
                    TMP, 0, 0, M, 256, 256, nullptr, 1, 2, skip + (l * 5 + 0), xs[0], stream);
        hipMemsetAsync(BNS, 0, 512 * 4, stream);
        bn_stats<<<120, 256, 0, stream>>>(TMP, BNS, M);
        bn_apply<<<2048, 256, 0, stream>>>(TMP, BNS, fbn_g + (l * 2 + 0) * 256, fbn_b + (l * 2 + 0) * 256, xs[0], M);
    }
}

// Round 2
// 4389.211 us; speedup vs baseline: 1.7365x; 1.7365x over previous
//
#include <hip/hip_runtime.h>
#include <math.h>

#define HID 256
#define EBUY 200000
#define NNODE 30000
static const size_t S = (size_t)NNODE * HID;   // 7,680,000 floats per node-feature tensor

__device__ __forceinline__ float gelu_f(float x) {
    return 0.5f * x * (1.0f + erff(x * 0.70710678118654752f));
}

// ---------------- GEMM: C[M,N] = op(A)[M,K] @ B[K,N] + bias ----------------
// EPI 0: D0[r*N+c] = v
// EPI 1: split into 256-col chunks -> D0, D1, D2
// EPI 2: skip-gate + residual: D0[r*256+c] = sg*v + (2-sg)*resid[r*256+c]
// GELU_A: apply exact gelu to A elements while staging into LDS.
template<int GELU_A, int EPI>
__launch_bounds__(256)
__global__ void gemm64(const float* __restrict__ A, const float* __restrict__ B,
                       const float* __restrict__ bias,
                       float* __restrict__ D0, float* __restrict__ D1, float* __restrict__ D2,
                       int M, int N, int K,
                       const int* __restrict__ gatherA,
                       const float* __restrict__ skipP, const float* __restrict__ resid)
{
    __shared__ float As[16][68];
    __shared__ float Bs[16][68];
    const int row0 = blockIdx.y * 64;
    const int col0 = blockIdx.x * 64;
    const int tid = threadIdx.x;
    const int tx = tid & 15, ty = tid >> 4;
    float acc[4][4] = {};

    for (int k0 = 0; k0 < K; k0 += 16) {
        #pragma unroll
        for (int i = 0; i < 4; ++i) {          // A tile: 64 rows x 16 k
            int e = tid + i * 256;
            int r = e >> 4, kk = e & 15;
            int gr = row0 + r;
            float v = 0.f;
            if (gr < M && (k0 + kk) < K) {
                int ar = gatherA ? gatherA[gr] : gr;
                v = A[(size_t)ar * K + k0 + kk];
            }
            if (GELU_A) v = gelu_f(v);
            As[kk][r] = v;
        }
        #pragma unroll
        for (int i = 0; i < 4; ++i) {          // B tile: 16 k x 64 cols
            int e = tid + i * 256;
            int kk = e >> 6, c = e & 63;
            float v = 0.f;
            if ((k0 + kk) < K && (col0 + c) < N)
                v = B[(size_t)(k0 + kk) * N + col0 + c];
            Bs[kk][c] = v;
        }
        __syncthreads();
        #pragma unroll
        for (int kk = 0; kk < 16; ++kk) {
            float4 a4 = *(const float4*)&As[kk][ty * 4];
            float4 b4 = *(const float4*)&Bs[kk][tx * 4];
            float a[4] = {a4.x, a4.y, a4.z, a4.w};
            float b[4] = {b4.x, b4.y, b4.z, b4.w};
            #pragma unroll
            for (int i = 0; i < 4; ++i)
                #pragma unroll
                for (int j = 0; j < 4; ++j)
                    acc[i][j] += a[i] * b[j];
        }
        __syncthreads();
    }

    float sg = 0.f;
    if (EPI == 2) sg = 1.f / (1.f + expf(-skipP[0]));
    #pragma unroll
    for (int i = 0; i < 4; ++i) {
        int r = row0 + ty * 4 + i;
        if (r >= M) continue;
        #pragma unroll
        for (int j = 0; j < 4; ++j) {
            int c = col0 + tx * 4 + j;
            if (c >= N) continue;
            float v = acc[i][j] + (bias ? bias[c] : 0.f);
            if (EPI == 0) {
                D0[(size_t)r * N + c] = v;
            } else if (EPI == 1) {
                float* D = (c < 256) ? D0 : ((c < 512) ? D1 : D2);
                D[(size_t)r * 256 + (c & 255)] = v;
            } else {
                float x = resid[(size_t)r * 256 + c];
                D0[(size_t)r * 256 + c] = sg * v + (2.f - sg) * x;
            }
        }
    }
}

// ------------- fuse k_rel/v_rel into kqv weights -------------
__global__ void build_fused(const float* __restrict__ W,    // [256,768] slice of kqv_W
                            const float* __restrict__ bvec, // [768] slice of kqv_b
                            const float* __restrict__ kR,   // [4,64,64] slice of k_rel
                            const float* __restrict__ vR,
                            float* __restrict__ Wf, float* __restrict__ bf,
                            int includeQ)
{
    int ncols = includeQ ? 768 : 512;
    int tid = blockIdx.x * 256 + threadIdx.x;
    int total = 257 * ncols;
    if (tid >= total) return;
    int r = tid / ncols, c = tid % ncols;
    int cb = c >> 8, cc = c & 255;
    int h = cc >> 6, dd = cc & 63;
    const float* Wrow = (r < 256) ? (W + (size_t)r * 768) : bvec;
    float out;
    if (includeQ && cb == 1) {
        out = Wrow[256 + cc];
    } else {
        const float* R = ((cb == 0) ? kR : vR) + (size_t)h * 64 * 64;
        int srcbase = (cb == 0) ? 0 : 512;
        float s = 0.f;
        #pragma unroll 8
        for (int d = 0; d < 64; ++d)
            s += Wrow[srcbase + h * 64 + d] * R[d * 64 + dd];
        out = s;
    }
    if (r < 256) Wf[(size_t)r * ncols + c] = out;
    else bf[c] = out;
}

// ------------- assoc logits (si = di = n): store raw logit, no atomics -------------
__global__ void logit_assoc(const float* __restrict__ q1, const float* __restrict__ ke,
                            const float* __restrict__ pRel,
                            float* __restrict__ logits)
{
    int g = blockIdx.x * 256 + threadIdx.x;
    int grp = g >> 4, lane = g & 15;
    if (grp >= NNODE * 4) return;
    int n = grp >> 2, h = grp & 3;
    float4 qv = *(const float4*)(q1 + (size_t)n * 256 + h * 64 + lane * 4);
    float4 kv = *(const float4*)(ke + (size_t)n * 256 + h * 64 + lane * 4);
    float d = qv.x * kv.x + qv.y * kv.y + qv.z * kv.z + qv.w * kv.w;
    for (int off = 8; off; off >>= 1) d += __shfl_xor(d, off, 16);
    if (lane == 0) logits[grp] = d * pRel[h] * 0.125f;
}

// ------------- CSR build for buys edges -------------
__global__ void edge_hist(const int* __restrict__ key, int* __restrict__ cnt, int E)
{
    int j = blockIdx.x * 256 + threadIdx.x;
    if (j < E) atomicAdd(&cnt[key[j]], 1);
}

__global__ void scan_excl(const int* __restrict__ cnt, int* __restrict__ off,
                          int* __restrict__ cursor, int N)
{
    __shared__ int sm[1024];
    __shared__ int carry;
    if (threadIdx.x == 0) carry = 0;
    __syncthreads();
    for (int base = 0; base < N; base += 1024) {
        int i = base + threadIdx.x;
        int v = (i < N) ? cnt[i] : 0;
        sm[threadIdx.x] = v;
        __syncthreads();
        for (int o = 1; o < 1024; o <<= 1) {
            int t = (threadIdx.x >= o) ? sm[threadIdx.x - o] : 0;
            __syncthreads();
            sm[threadIdx.x] += t;
            __syncthreads();
        }
        if (i < N) {
            int ex = carry + sm[threadIdx.x] - v;
            off[i] = ex;
            cursor[i] = ex;
        }
        __syncthreads();
        if (threadIdx.x == 0) carry += sm[1023];
        __syncthreads();
    }
    if (threadIdx.x == 0) off[N] = carry;
}

__global__ void edge_place(const int* __restrict__ key, int* __restrict__ cursor,
                           int* __restrict__ eid, int E)
{
    int j = blockIdx.x * 256 + threadIdx.x;
    if (j < E) {
        int pos = atomicAdd(&cursor[key[j]], 1);
        eid[pos] = j;
    }
}

// ------------- fused attention gather: one wave per dst node -------------
// online softmax over: (optional) 3 assoc edges (precomputed logits + VEassoc) + CSR buys edges.
// lane l: head h=l>>4, dims (l&15)*4 .. +3 of that head.
template<int HAS_ASSOC>
__launch_bounds__(256)
__global__ void attn_gather(const float* __restrict__ Qd,   // [N,256] q of dst type
                            const float* __restrict__ KEs,  // [N,256] rel-k of buys src type
                            const float* __restrict__ VEs,  // [N,256] rel-v of buys src type
                            const float* __restrict__ LIass,   // [3][N*4] assoc logits
                            const float* __restrict__ VEassoc, // VE base for types 2..4 (stride S)
                            const int* __restrict__ roff, const int* __restrict__ eids,
                            const int* __restrict__ other,     // src node of each buys edge
                            const float* __restrict__ pRelBuys,
                            float* __restrict__ AGG)
{
    int wid = (blockIdx.x * 256 + threadIdx.x) >> 6;
    int lane = threadIdx.x & 63;
    if (wid >= NNODE) return;
    int h = lane >> 4;

    float4 q = *(const float4*)(Qd + (size_t)wid * 256 + lane * 4);
    float m = -INFINITY, s = 0.f;
    float4 acc = {0.f, 0.f, 0.f, 0.f};

    if (HAS_ASSOC) {
        #pragma unroll
        for (int e = 0; e < 3; ++e) {
            float lg = LIass[e * (NNODE * 4) + wid * 4 + h];
            float4 v4 = *(const float4*)(VEassoc + (size_t)e * S + (size_t)wid * 256 + lane * 4);
            float mn = fmaxf(m, lg);
            float so = __expf(m - mn);
            float ev = __expf(lg - mn);
            s = s * so + ev;
            acc.x = acc.x * so + ev * v4.x;
            acc.y = acc.y * so + ev * v4.y;
            acc.z = acc.z * so + ev * v4.z;
            acc.w = acc.w * so + ev * v4.w;
            m = mn;
        }
    }

    float pb = pRelBuys[h] * 0.125f;
    int j1 = roff[wid + 1];
    for (int j = roff[wid]; j < j1; ++j) {
        int src = other[eids[j]];
        float4 k4 = *(const float4*)(KEs + (size_t)src * 256 + lane * 4);
        float d = q.x * k4.x + q.y * k4.y + q.z * k4.z + q.w * k4.w;
        for (int off = 8; off; off >>= 1) d += __shfl_xor(d, off, 16);
        float lg = d * pb;
        float4 v4 = *(const float4*)(VEs + (size_t)src * 256 + lane * 4);
        float mn = fmaxf(m, lg);
        float so = __expf(m - mn);
        float ev = __expf(lg - mn);
        s = s * so + ev;
        acc.x = acc.x * so + ev * v4.x;
        acc.y = acc.y * so + ev * v4.y;
        acc.z = acc.z * so + ev * v4.z;
        acc.w = acc.w * so + ev * v4.w;
        m = mn;
    }

    float inv = 1.f / (s + 1e-16f);
    float4 o4 = {acc.x * inv, acc.y * inv, acc.z * inv, acc.w * inv};
    *(float4*)(AGG + (size_t)wid * 256 + lane * 4) = o4;
}

// ------------- batch-norm -------------
__global__ void bn_stats(const float* __restrict__ x, float* __restrict__ sums, int M)
{
    int col = threadIdx.x;
    int rpb = (M + gridDim.x - 1) / gridDim.x;
    int r0 = blockIdx.x * rpb, r1 = min(M, r0 + rpb);
    float s = 0.f, s2 = 0.f;
    for (int r = r0; r < r1; ++r) {
        float v = x[(size_t)r * 256 + col];
        s += v; s2 += v * v;
    }
    atomicAdd(&sums[col], s);
    atomicAdd(&sums[256 + col], s2);
}

__global__ void bn_apply(const float* __restrict__ x, const float* __restrict__ sums,
                         const float* __restrict__ g, const float* __restrict__ b,
                         float* __restrict__ y, int M)
{
    size_t total = (size_t)M * 256;
    int col = threadIdx.x & 255;
    float mu = sums[col] / (float)M;
    float var = sums[256 + col] / (float)M - mu * mu;
    float sc = rsqrtf(var + 1e-5f) * g[col];
    float sh = b[col];
    for (size_t i = (size_t)blockIdx.x * 256 + threadIdx.x; i < total; i += (size_t)gridDim.x * 256) {
        float v = (x[i] - mu) * sc + sh;
        y[i] = fmaxf(v, 0.f);
    }
}

// ---------------- host orchestration ----------------
static inline void launch_gemm(const float* A, const float* B, const float* bias,
                               float* D0, float* D1, float* D2,
                               int M, int N, int K, const int* gather,
                               int gelu, int epi, const float* skipP, const float* resid,
                               hipStream_t stream)
{
    dim3 grid((N + 63) / 64, (M + 63) / 64);
    dim3 blk(256);
    if (gelu == 0 && epi == 0)
        hipLaunchKernelGGL((gemm64<0, 0>), grid, blk, 0, stream, A, B, bias, D0, D1, D2, M, N, K, gather, skipP, resid);
    else if (gelu == 0 && epi == 1)
        hipLaunchKernelGGL((gemm64<0, 1>), grid, blk, 0, stream, A, B, bias, D0, D1, D2, M, N, K, gather, skipP, resid);
    else
        hipLaunchKernelGGL((gemm64<1, 2>), grid, blk, 0, stream, A, B, bias, D0, D1, D2, M, N, K, gather, skipP, resid);
}

extern "C" void kernel_launch(void* const* d_in, const int* in_sizes, int n_in,
                              void* d_out, int out_size, void* d_ws, size_t ws_size,
                              hipStream_t stream)
{
    const int*   user_id    = (const int*)d_in[0];
    const int*   item_id    = (const int*)d_in[1];
    const int*   buys_src   = (const int*)d_in[2];
    const int*   buys_dst   = (const int*)d_in[3];
    const float* image_feat = (const float*)d_in[4];
    const float* taste_feat = (const float*)d_in[5];
    const float* intent_feat= (const float*)d_in[6];
    const float* user_emb   = (const float*)d_in[7];
    const float* user_W     = (const float*)d_in[8];
    const float* user_b     = (const float*)d_in[9];
    const float* user_bn_g  = (const float*)d_in[10];
    const float* user_bn_b  = (const float*)d_in[11];
    const float* item_emb   = (const float*)d_in[12];
    const float* item_W     = (const float*)d_in[13];
    const float* item_b     = (const float*)d_in[14];
    const float* item_bn_g  = (const float*)d_in[15];
    const float* item_bn_b  = (const float*)d_in[16];
    const float* img_U      = (const float*)d_in[17];
    const float* img_V      = (const float*)d_in[18];
    const float* img_b      = (const float*)d_in[19];
    const float* taste_W    = (const float*)d_in[20];
    const float* taste_b    = (const float*)d_in[21];
    const float* intent_W   = (const float*)d_in[22];
    const float* intent_b   = (const float*)d_in[23];
    const float* kqv_W      = (const float*)d_in[24];
    const float* kqv_b      = (const float*)d_in[25];
    const float* out_W      = (const float*)d_in[26];
    const float* out_b      = (const float*)d_in[27];
    const float* k_rel      = (const float*)d_in[28];
    const float* v_rel      = (const float*)d_in[29];
    const float* p_rel      = (const float*)d_in[30];
    const float* skip       = (const float*)d_in[31];
    const float* fbn_g      = (const float*)d_in[32];
    const float* fbn_b      = (const float*)d_in[33];

    float* out = (float*)d_out;
    float* ws  = (float*)d_ws;

    float* VE  = ws;             // 5S : relation-transformed v per source type
    float* Q   = ws + 5 * S;     // 2S : q for types 0,1
    float* KE  = ws + 7 * S;     // 2S : rel-k for types 0,1 (slot0 reused as TMP)
    float* AGG = ws + 9 * S;     // 1S
    float* TMP = KE;             // alias
    float* Wf  = ws + 10 * S;    // 196608
    float* bf  = Wf + 196608;    // 768
    float* LI  = bf + 768;       // assoc logits: 3 x 120000
    float* BNS = LI + 360000;    // 512
    int* cnt_i = (int*)(BNS + 512);      // 30000
    int* off_i = cnt_i + NNODE;          // 30001
    int* cur_i = off_i + NNODE + 1;      // 30000
    int* eid_i = cur_i + NNODE;          // 200000
    int* cnt_u = eid_i + EBUY;           // 30000
    int* off_u = cnt_u + NNODE;          // 30001
    int* cur_u = off_u + NNODE + 1;      // 30000
    int* eid_u = cur_u + NNODE;          // 200000

    size_t need = (size_t)((char*)(eid_u + EBUY) - (char*)ws);
    if (ws_size < need) return;

    float* xs[5] = { out, out + S, out + 2 * S, out + 3 * S, out + 4 * S };
    const int M = NNODE;

    // ---------------- CSR for buys (both orientations), once ----------------
    hipMemsetAsync(cnt_i, 0, NNODE * 4, stream);
    hipMemsetAsync(cnt_u, 0, NNODE * 4, stream);
    {
        int eb = (EBUY + 255) / 256;
        edge_hist<<<eb, 256, 0, stream>>>(buys_dst, cnt_i, EBUY);
        edge_hist<<<eb, 256, 0, stream>>>(buys_src, cnt_u, EBUY);
        scan_excl<<<1, 1024, 0, stream>>>(cnt_i, off_i, cur_i, NNODE);
        scan_excl<<<1, 1024, 0, stream>>>(cnt_u, off_u, cur_u, NNODE);
        edge_place<<<eb, 256, 0, stream>>>(buys_dst, cur_i, eid_i, EBUY);
        edge_place<<<eb, 256, 0, stream>>>(buys_src, cur_u, eid_u, EBUY);
    }

    // ---------------- encoders ----------------
    launch_gemm(taste_feat, taste_W, taste_b, xs[2], 0, 0, M, 256, 768, nullptr, 0, 0, 0, 0, stream);
    launch_gemm(intent_feat, intent_W, intent_b, xs[3], 0, 0, M, 256, 20, nullptr, 0, 0, 0, 0, stream);
    launch_gemm(image_feat, img_U, nullptr, TMP, 0, 0, M, 64, 512, nullptr, 0, 0, 0, 0, stream);
    launch_gemm(TMP, img_V, img_b, xs[4], 0, 0, M, 256, 64, nullptr, 0, 0, 0, 0, stream);
    launch_gemm(user_emb, user_W, user_b, TMP, 0, 0, M, 256, 64, user_id, 0, 0, 0, 0, stream);
    hipMemsetAsync(BNS, 0, 512 * 4, stream);
    bn_stats<<<120, 256, 0, stream>>>(TMP, BNS, M);
    bn_apply<<<2048, 256, 0, stream>>>(TMP, BNS, user_bn_g, user_bn_b, xs[0], M);
    launch_gemm(item_emb, item_W, item_b, TMP, 0, 0, M, 256, 64, item_id, 0, 0, 0, 0, stream);
    hipMemsetAsync(BNS, 0, 512 * 4, stream);
    bn_stats<<<120, 256, 0, stream>>>(TMP, BNS, M);
    bn_apply<<<2048, 256, 0, stream>>>(TMP, BNS, item_bn_g, item_bn_b, xs[1], M);

    // ---------------- layers ----------------
    static const int esrc[5] = {3, 4, 0, 1, 2};  // src type t -> edge index
    for (int l = 0; l < 2; ++l) {
        // t = 0,1 : produce KE[t], Q[t], VE[t]
        for (int t = 0; t < 2; ++t) {
            int e = esrc[t];
            build_fused<<<(257 * 768 + 255) / 256, 256, 0, stream>>>(
                kqv_W + (size_t)(l * 5 + t) * 256 * 768, kqv_b + (size_t)(l * 5 + t) * 768,
                k_rel + (size_t)(l * 5 + e) * 4 * 64 * 64, v_rel + (size_t)(l * 5 + e) * 4 * 64 * 64,
                Wf, bf, 1);
            launch_gemm(xs[t], Wf, bf, KE + t * S, Q + t * S, VE + t * S, M, 768, 256,
                        nullptr, 0, 1, 0, 0, stream);
        }
        // t = 2..4 : KE not needed (assoc logits immediate); reuse a scratch slot trick:
        // rel-k lands in AGG (scratch), VE in its slot; logits computed right away.
        for (int t = 2; t < 5; ++t) {
            int e = esrc[t];  // 0,1,2
            build_fused<<<(257 * 512 + 255) / 256, 256, 0, stream>>>(
                kqv_W + (size_t)(l * 5 + t) * 256 * 768, kqv_b + (size_t)(l * 5 + t) * 768,
                k_rel + (size_t)(l * 5 + e) * 4 * 64 * 64, v_rel + (size_t)(l * 5 + e) * 4 * 64 * 64,
                Wf, bf, 0);
            launch_gemm(xs[t], Wf, bf, AGG, VE + t * S, nullptr, M, 512, 256,
                        nullptr, 0, 1, 0, 0, stream);
            int blocks = (NNODE * 4 * 16 + 255) / 256;
            logit_assoc<<<blocks, 256, 0, stream>>>(Q + S, AGG, p_rel + (l * 5 + e) * 4,
                                                    LI + e * 120000);
        }
        // dst = item : fused online-softmax gather (3 assoc + buys CSR)
        {
            int blocks = (NNODE * 64 + 255) / 256;
            hipLaunchKernelGGL((attn_gather<1>), dim3(blocks), dim3(256), 0, stream,
                Q + S, KE, VE, LI, VE + 2 * S, off_i, eid_i, buys_src,
                p_rel + (size_t)(l * 5 + 3) * 4, AGG);
        }
        launch_gemm(AGG, out_W + (size_t)(l * 5 + 1) * 65536, out_b + (l * 5 + 1) * 256,
                    TMP, 0, 0, M, 256, 256, nullptr, 1, 2, skip + (l * 5 + 1), xs[1], stream);
        hipMemsetAsync(BNS, 0, 512 * 4, stream);
        bn_stats<<<120, 256, 0, stream>>>(TMP, BNS, M);
        bn_apply<<<2048, 256, 0, stream>>>(TMP, BNS, fbn_g + (l * 2 + 1) * 256, fbn_b + (l * 2 + 1) * 256, xs[1], M);
        // dst = user : buys-reverse only
        {
            int blocks = (NNODE * 64 + 255) / 256;
            hipLaunchKernelGGL((attn_gather<0>), dim3(blocks), dim3(256), 0, stream,
                Q, KE + S, VE + S, nullptr, nullptr, off_u, eid_u, buys_dst,
                p_rel + (size_t)(l * 5 + 4) * 4, AGG);
        }
        launch_gemm(AGG, out_W + (size_t)(l * 5 + 0) * 65536, out_b + (l * 5 + 0) * 256,
                    TMP, 0, 0, M, 256, 256, nullptr, 1, 2, skip + (l * 5 + 0), xs[0], stream);
        hipMemsetAsync(BNS, 0, 512 * 4, stream);
        bn_stats<<<120, 256, 0, stream>>>(TMP, BNS, M);
        bn_apply<<<2048, 256, 0, stream>>>(TMP, BNS, fbn_g + (l * 2 + 0) * 256, fbn_b + (l * 2 + 0) * 256, xs[0], M);
    }
}

// Round 3
// 1882.011 us; speedup vs baseline: 4.0498x; 2.3322x over previous
//
#include <hip/hip_runtime.h>
#include <math.h>

#define HID 256
#define EBUY 200000
#define NNODE 30000
static const size_t S = (size_t)NNODE * HID;   // 7,680,000 floats

typedef __attribute__((ext_vector_type(8))) short  short8;
typedef __attribute__((ext_vector_type(4))) float  f32x4;

__device__ __forceinline__ float gelu_f(float x) {
    return 0.5f * x * (1.0f + erff(x * 0.70710678118654752f));
}
__device__ __forceinline__ unsigned short f2bf(float f) {
    unsigned u = __float_as_uint(f);
    u = (u + 0x7FFFu + ((u >> 16) & 1u)) >> 16;
    return (unsigned short)u;
}
__device__ __forceinline__ float b2f(unsigned short us) {
    return __uint_as_float((unsigned)us << 16);
}

// ---------------- conversions ----------------
__global__ void convf4(const float* __restrict__ in, unsigned short* __restrict__ o, int n4)
{
    int i = blockIdx.x * 256 + threadIdx.x;
    if (i >= n4) return;
    float4 v = ((const float4*)in)[i];
    ushort4 u; u.x = f2bf(v.x); u.y = f2bf(v.y); u.z = f2bf(v.z); u.w = f2bf(v.w);
    ((ushort4*)o)[i] = u;
}

__global__ void conv_pad(const float* __restrict__ in, unsigned short* __restrict__ o,
                         int M, int K, int Kpad)
{
    int i = blockIdx.x * 256 + threadIdx.x;
    if (i >= M * Kpad) return;
    int r = i / Kpad, k = i % Kpad;
    o[i] = (k < K) ? f2bf(in[(size_t)r * K + k]) : (unsigned short)0;
}

// W [K,N] f32 -> WT [N,Kpad] bf16 (zero-padded K)
__global__ void wtconv(const float* __restrict__ W, unsigned short* __restrict__ WT,
                       int K, int N, int Kpad)
{
    int i = blockIdx.x * 256 + threadIdx.x;
    if (i >= N * Kpad) return;
    int n = i / Kpad, k = i % Kpad;
    WT[i] = (k < K) ? f2bf(W[(size_t)k * N + n]) : (unsigned short)0;
}

// ------------- fuse k_rel/v_rel into kqv weights, emit transposed bf16 -------------
// includeQ: cols [0,256)=k@R, [256,512)=q, [512,768)=v@R ; else [0,256)=k@R, [256,512)=v@R
// WT [ncols, 256] bf16 ; bfv [ncols] f32
__global__ void build_fusedT(const float* __restrict__ W,    // [256,768]
                             const float* __restrict__ bvec, // [768]
                             const float* __restrict__ kR,   // [4,64,64]
                             const float* __restrict__ vR,
                             unsigned short* __restrict__ WT, float* __restrict__ bfv,
                             int includeQ)
{
    int ncols = includeQ ? 768 : 512;
    int tid = blockIdx.x * 256 + threadIdx.x;
    int total = 257 * ncols;
    if (tid >= total) return;
    int r = tid / ncols, c = tid % ncols;
    int cb = c >> 8, cc = c & 255;
    int h = cc >> 6, dd = cc & 63;
    const float* Wrow = (r < 256) ? (W + (size_t)r * 768) : bvec;
    float out;
    if (includeQ && cb == 1) {
        out = Wrow[256 + cc];
    } else {
        const float* R = ((cb == 0) ? kR : vR) + (size_t)h * 64 * 64;
        int srcbase = (cb == 0) ? 0 : 512;
        float s = 0.f;
        #pragma unroll 8
        for (int d = 0; d < 64; ++d)
            s += Wrow[srcbase + h * 64 + d] * R[d * 64 + dd];
        out = s;
    }
    if (r < 256) WT[(size_t)c * 256 + r] = f2bf(out);
    else bfv[c] = out;
}

// ---------------- bf16 MFMA GEMM ----------------
// C[M,N] = A[M,K](bf16) @ BT[N,K](bf16)^T + bias
// 128x128 tile, BK=32, 256 thr = 4 waves (2x2), wave = 64x64 = 4x4 frags 16x16x32.
// EPI 0: D0 f32 [M,N]
// EPI 1: c<256 -> D0 f32 ; c<512 -> D1 f32 ; else -> Db bf16   (ncols=768 kqv)
// EPI 3: c<256 -> D0 f32 ; else -> Db bf16                     (ncols=512 kv)
// EPI 2: D0 = sg*v + (2-sg)*resid  (skip+residual)
#define KPAD 40
template<int EPI>
__launch_bounds__(256)
__global__ void gemm_mfma(const unsigned short* __restrict__ A,
                          const unsigned short* __restrict__ BT,
                          const float* __restrict__ bias,
                          float* __restrict__ D0, float* __restrict__ D1,
                          unsigned short* __restrict__ Db,
                          int M, int N, int K,
                          const int* __restrict__ gatherA,
                          const float* __restrict__ skipP, const float* __restrict__ resid)
{
    __shared__ unsigned short Asl[128 * KPAD];
    __shared__ unsigned short Bsl[128 * KPAD];
    const int tid = threadIdx.x;
    const int row0 = blockIdx.y * 128, col0 = blockIdx.x * 128;
    const int wid = tid >> 6, lane = tid & 63;
    const int wr = wid >> 1, wc = wid & 1;
    const int l16 = lane & 15, kg = lane >> 4;

    f32x4 acc[4][4];
    const f32x4 zero = {0.f, 0.f, 0.f, 0.f};
    #pragma unroll
    for (int i = 0; i < 4; ++i)
        #pragma unroll
        for (int j = 0; j < 4; ++j) acc[i][j] = zero;

    // staging: 512 chunks of 16B (row = c>>2, kq = c&3); 2 per thread
    const int rA0 = tid >> 2, rA1 = (tid + 256) >> 2;
    const int q0 = tid & 3;   // same for both chunks (+256 keeps low bits)
    int gr0 = min(row0 + rA0, M - 1), gr1 = min(row0 + rA1, M - 1);
    if (gatherA) { gr0 = gatherA[gr0]; gr1 = gatherA[gr1]; }
    const int gc0 = min(col0 + rA0, N - 1), gc1 = min(col0 + rA1, N - 1);

    for (int k0 = 0; k0 < K; k0 += 32) {
        *(uint4*)&Asl[rA0 * KPAD + q0 * 8] = *(const uint4*)&A[(size_t)gr0 * K + k0 + q0 * 8];
        *(uint4*)&Asl[rA1 * KPAD + q0 * 8] = *(const uint4*)&A[(size_t)gr1 * K + k0 + q0 * 8];
        *(uint4*)&Bsl[rA0 * KPAD + q0 * 8] = *(const uint4*)&BT[(size_t)gc0 * K + k0 + q0 * 8];
        *(uint4*)&Bsl[rA1 * KPAD + q0 * 8] = *(const uint4*)&BT[(size_t)gc1 * K + k0 + q0 * 8];
        __syncthreads();
        short8 af[4], bfr[4];
        #pragma unroll
        for (int i = 0; i < 4; ++i) {
            af[i]  = *(const short8*)&Asl[(wr * 64 + i * 16 + l16) * KPAD + kg * 8];
            bfr[i] = *(const short8*)&Bsl[(wc * 64 + i * 16 + l16) * KPAD + kg * 8];
        }
        #pragma unroll
        for (int i = 0; i < 4; ++i)
            #pragma unroll
            for (int j = 0; j < 4; ++j)
                acc[i][j] = __builtin_amdgcn_mfma_f32_16x16x32_bf16(af[i], bfr[j], acc[i][j], 0, 0, 0);
        __syncthreads();
    }

    float sg = 0.f;
    if (EPI == 2) sg = 1.f / (1.f + __expf(-skipP[0]));
    const int rbase = row0 + wr * 64, cbase = col0 + wc * 64;
    #pragma unroll
    for (int j = 0; j < 4; ++j) {
        int cc = cbase + j * 16 + l16;
        if (cc >= N) continue;
        float bv = bias ? bias[cc] : 0.f;
        #pragma unroll
        for (int i = 0; i < 4; ++i) {
            #pragma unroll
            for (int r = 0; r < 4; ++r) {
                int rr = rbase + i * 16 + kg * 4 + r;
                if (rr >= M) continue;
                float v = acc[i][j][r] + bv;
                if (EPI == 0) {
                    D0[(size_t)rr * N + cc] = v;
                } else if (EPI == 1) {
                    if (cc < 256)      D0[(size_t)rr * 256 + cc] = v;
                    else if (cc < 512) D1[(size_t)rr * 256 + (cc - 256)] = v;
                    else               Db[(size_t)rr * 256 + (cc - 512)] = f2bf(v);
                } else if (EPI == 3) {
                    if (cc < 256)      D0[(size_t)rr * 256 + cc] = v;
                    else               Db[(size_t)rr * 256 + (cc - 256)] = f2bf(v);
                } else {
                    float x = resid[(size_t)rr * 256 + cc];
                    D0[(size_t)rr * 256 + cc] = sg * v + (2.f - sg) * x;
                }
            }
        }
    }
}

// ------------- assoc logits -------------
__global__ void logit_assoc(const float* __restrict__ q1, const float* __restrict__ ke,
                            const float* __restrict__ pRel, float* __restrict__ logits)
{
    int g = blockIdx.x * 256 + threadIdx.x;
    int grp = g >> 4, lane = g & 15;
    if (grp >= NNODE * 4) return;
    int n = grp >> 2, h = grp & 3;
    float4 qv = *(const float4*)(q1 + (size_t)n * 256 + h * 64 + lane * 4);
    float4 kv = *(const float4*)(ke + (size_t)n * 256 + h * 64 + lane * 4);
    float d = qv.x * kv.x + qv.y * kv.y + qv.z * kv.z + qv.w * kv.w;
    for (int off = 8; off; off >>= 1) d += __shfl_xor(d, off, 16);
    if (lane == 0) logits[grp] = d * pRel[h] * 0.125f;
}

// ------------- CSR build -------------
__global__ void edge_hist(const int* __restrict__ key, int* __restrict__ cnt, int E)
{
    int j = blockIdx.x * 256 + threadIdx.x;
    if (j < E) atomicAdd(&cnt[key[j]], 1);
}

__global__ void scan_excl(const int* __restrict__ cnt, int* __restrict__ off,
                          int* __restrict__ cursor, int N)
{
    __shared__ int sm[1024];
    __shared__ int carry;
    if (threadIdx.x == 0) carry = 0;
    __syncthreads();
    for (int base = 0; base < N; base += 1024) {
        int i = base + threadIdx.x;
        int v = (i < N) ? cnt[i] : 0;
        sm[threadIdx.x] = v;
        __syncthreads();
        for (int o = 1; o < 1024; o <<= 1) {
            int t = (threadIdx.x >= o) ? sm[threadIdx.x - o] : 0;
            __syncthreads();
            sm[threadIdx.x] += t;
            __syncthreads();
        }
        if (i < N) {
            int ex = carry + sm[threadIdx.x] - v;
            off[i] = ex;
            cursor[i] = ex;
        }
        __syncthreads();
        if (threadIdx.x == 0) carry += sm[1023];
        __syncthreads();
    }
    if (threadIdx.x == 0) off[N] = carry;
}

__global__ void edge_place(const int* __restrict__ key, int* __restrict__ cursor,
                           int* __restrict__ eid, int E)
{
    int j = blockIdx.x * 256 + threadIdx.x;
    if (j < E) {
        int pos = atomicAdd(&cursor[key[j]], 1);
        eid[pos] = j;
    }
}

// ------------- fused attention gather (online softmax), writes gelu(out) bf16 -------------
template<int HAS_ASSOC>
__launch_bounds__(256)
__global__ void attn_gather(const float* __restrict__ Qd,
                            const float* __restrict__ KEs,            // f32 rel-k of buys src
                            const unsigned short* __restrict__ VEs,   // bf16 rel-v of buys src
                            const float* __restrict__ LIass,
                            const unsigned short* __restrict__ VEassoc, // bf16 base (stride S)
                            const int* __restrict__ roff, const int* __restrict__ eids,
                            const int* __restrict__ other,
                            const float* __restrict__ pRelBuys,
                            unsigned short* __restrict__ AGGb)
{
    int wid = (blockIdx.x * 256 + threadIdx.x) >> 6;
    int lane = threadIdx.x & 63;
    if (wid >= NNODE) return;
    int h = lane >> 4;

    float4 q = *(const float4*)(Qd + (size_t)wid * 256 + lane * 4);
    float m = -INFINITY, s = 0.f;
    float4 acc = {0.f, 0.f, 0.f, 0.f};

    if (HAS_ASSOC) {
        #pragma unroll
        for (int e = 0; e < 3; ++e) {
            float lg = LIass[e * (NNODE * 4) + wid * 4 + h];
            ushort4 vv = *(const ushort4*)(VEassoc + (size_t)e * S + (size_t)wid * 256 + lane * 4);
            float mn = fmaxf(m, lg);
            float so = __expf(m - mn);
            float ev = __expf(lg - mn);
            s = s * so + ev;
            acc.x = acc.x * so + ev * b2f(vv.x);
            acc.y = acc.y * so + ev * b2f(vv.y);
            acc.z = acc.z * so + ev * b2f(vv.z);
            acc.w = acc.w * so + ev * b2f(vv.w);
            m = mn;
        }
    }

    float pb = pRelBuys[h] * 0.125f;
    int j1 = roff[wid + 1];
    for (int j = roff[wid]; j < j1; ++j) {
        int src = other[eids[j]];
        float4 k4 = *(const float4*)(KEs + (size_t)src * 256 + lane * 4);
        float d = q.x * k4.x + q.y * k4.y + q.z * k4.z + q.w * k4.w;
        for (int off = 8; off; off >>= 1) d += __shfl_xor(d, off, 16);
        float lg = d * pb;
        ushort4 vv = *(const ushort4*)(VEs + (size_t)src * 256 + lane * 4);
        float mn = fmaxf(m, lg);
        float so = __expf(m - mn);
        float ev = __expf(lg - mn);
        s = s * so + ev;
        acc.x = acc.x * so + ev * b2f(vv.x);
        acc.y = acc.y * so + ev * b2f(vv.y);
        acc.z = acc.z * so + ev * b2f(vv.z);
        acc.w = acc.w * so + ev * b2f(vv.w);
        m = mn;
    }

    float inv = 1.f / (s + 1e-16f);
    ushort4 o4;
    o4.x = f2bf(gelu_f(acc.x * inv));
    o4.y = f2bf(gelu_f(acc.y * inv));
    o4.z = f2bf(gelu_f(acc.z * inv));
    o4.w = f2bf(gelu_f(acc.w * inv));
    *(ushort4*)(AGGb + (size_t)wid * 256 + lane * 4) = o4;
}

// ------------- batch-norm -------------
__global__ void bn_stats(const float* __restrict__ x, float* __restrict__ sums, int M)
{
    int col = threadIdx.x;
    int rpb = (M + gridDim.x - 1) / gridDim.x;
    int r0 = blockIdx.x * rpb, r1 = min(M, r0 + rpb);
    float s = 0.f, s2 = 0.f;
    for (int r = r0; r < r1; ++r) {
        float v = x[(size_t)r * 256 + col];
        s += v; s2 += v * v;
    }
    atomicAdd(&sums[col], s);
    atomicAdd(&sums[256 + col], s2);
}

__global__ void bn_apply(const float* __restrict__ x, const float* __restrict__ sums,
                         const float* __restrict__ g, const float* __restrict__ b,
                         float* __restrict__ y, int M)
{
    size_t total = (size_t)M * 256;
    int col = threadIdx.x & 255;
    float mu = sums[col] / (float)M;
    float var = sums[256 + col] / (float)M - mu * mu;
    float sc = rsqrtf(var + 1e-5f) * g[col];
    float sh = b[col];
    for (size_t i = (size_t)blockIdx.x * 256 + threadIdx.x; i < total; i += (size_t)gridDim.x * 256) {
        float v = (x[i] - mu) * sc + sh;
        y[i] = fmaxf(v, 0.f);
    }
}

// ---------------- host orchestration ----------------
static inline void launch_gemm(const unsigned short* A, const unsigned short* BT,
                               const float* bias, float* D0, float* D1, unsigned short* Db,
                               int M, int N, int K, const int* gather, int epi,
                               const float* skipP, const float* resid, hipStream_t stream)
{
    dim3 grid((N + 127) / 128, (M + 127) / 128);
    dim3 blk(256);
    switch (epi) {
    case 0: hipLaunchKernelGGL((gemm_mfma<0>), grid, blk, 0, stream, A, BT, bias, D0, D1, Db, M, N, K, gather, skipP, resid); break;
    case 1: hipLaunchKernelGGL((gemm_mfma<1>), grid, blk, 0, stream, A, BT, bias, D0, D1, Db, M, N, K, gather, skipP, resid); break;
    case 2: hipLaunchKernelGGL((gemm_mfma<2>), grid, blk, 0, stream, A, BT, bias, D0, D1, Db, M, N, K, gather, skipP, resid); break;
    default:hipLaunchKernelGGL((gemm_mfma<3>), grid, blk, 0, stream, A, BT, bias, D0, D1, Db, M, N, K, gather, skipP, resid); break;
    }
}

extern "C" void kernel_launch(void* const* d_in, const int* in_sizes, int n_in,
                              void* d_out, int out_size, void* d_ws, size_t ws_size,
                              hipStream_t stream)
{
    const int*   user_id    = (const int*)d_in[0];
    const int*   item_id    = (const int*)d_in[1];
    const int*   buys_src   = (const int*)d_in[2];
    const int*   buys_dst   = (const int*)d_in[3];
    const float* image_feat = (const float*)d_in[4];
    const float* taste_feat = (const float*)d_in[5];
    const float* intent_feat= (const float*)d_in[6];
    const float* user_emb   = (const float*)d_in[7];
    const float* user_W     = (const float*)d_in[8];
    const float* user_b     = (const float*)d_in[9];
    const float* user_bn_g  = (const float*)d_in[10];
    const float* user_bn_b  = (const float*)d_in[11];
    const float* item_emb   = (const float*)d_in[12];
    const float* item_W     = (const float*)d_in[13];
    const float* item_b     = (const float*)d_in[14];
    const float* item_bn_g  = (const float*)d_in[15];
    const float* item_bn_b  = (const float*)d_in[16];
    const float* img_U      = (const float*)d_in[17];
    const float* img_V      = (const float*)d_in[18];
    const float* img_b      = (const float*)d_in[19];
    const float* taste_W    = (const float*)d_in[20];
    const float* taste_b    = (const float*)d_in[21];
    const float* intent_W   = (const float*)d_in[22];
    const float* intent_b   = (const float*)d_in[23];
    const float* kqv_W      = (const float*)d_in[24];
    const float* kqv_b      = (const float*)d_in[25];
    const float* out_W      = (const float*)d_in[26];
    const float* out_b      = (const float*)d_in[27];
    const float* k_rel      = (const float*)d_in[28];
    const float* v_rel      = (const float*)d_in[29];
    const float* p_rel      = (const float*)d_in[30];
    const float* skip       = (const float*)d_in[31];
    const float* fbn_g      = (const float*)d_in[32];
    const float* fbn_b      = (const float*)d_in[33];

    float* out = (float*)d_out;
    float* ws  = (float*)d_ws;

    float* Q   = ws;                 // 2S f32: q for types 0,1
    float* KE  = ws + 2 * S;         // 2S f32: rel-k for types 0,1
    float* SCR = ws + 4 * S;         // 1S f32: rel-k scratch (t>=2) / TMP
    unsigned short* VEb = (unsigned short*)(ws + 5 * S);   // 5S bf16: rel-v all types
    unsigned short* ABF = VEb + 5 * S;                     // 23,040,000 bf16 scratch (A operand)
    unsigned short* WT  = ABF + 23040000;                  // 196,608 bf16
    float* bfv = (float*)(WT + 196608);                    // 768 f32
    float* LI  = bfv + 768;                                // 360,000 f32
    float* BNS = LI + 360000;                              // 512
    int* cnt_i = (int*)(BNS + 512);
    int* off_i = cnt_i + NNODE;
    int* cur_i = off_i + NNODE + 1;
    int* eid_i = cur_i + NNODE;
    int* cnt_u = eid_i + EBUY;
    int* off_u = cnt_u + NNODE;
    int* cur_u = off_u + NNODE + 1;
    int* eid_u = cur_u + NNODE;

    size_t need = (size_t)((char*)(eid_u + EBUY) - (char*)ws);
    if (ws_size < need) return;

    float* xs[5] = { out, out + S, out + 2 * S, out + 3 * S, out + 4 * S };
    const int M = NNODE;

    // ---------------- CSR for buys ----------------
    hipMemsetAsync(cnt_i, 0, NNODE * 4, stream);
    hipMemsetAsync(cnt_u, 0, NNODE * 4, stream);
    {
        int eb = (EBUY + 255) / 256;
        edge_hist<<<eb, 256, 0, stream>>>(buys_dst, cnt_i, EBUY);
        edge_hist<<<eb, 256, 0, stream>>>(buys_src, cnt_u, EBUY);
        scan_excl<<<1, 1024, 0, stream>>>(cnt_i, off_i, cur_i, NNODE);
        scan_excl<<<1, 1024, 0, stream>>>(cnt_u, off_u, cur_u, NNODE);
        edge_place<<<eb, 256, 0, stream>>>(buys_dst, cur_i, eid_i, EBUY);
        edge_place<<<eb, 256, 0, stream>>>(buys_src, cur_u, eid_u, EBUY);
    }

    // ---------------- encoders ----------------
    // taste
    convf4<<<(23040000 / 4 + 255) / 256, 256, 0, stream>>>(taste_feat, ABF, 23040000 / 4);
    wtconv<<<(256 * 768 + 255) / 256, 256, 0, stream>>>(taste_W, WT, 768, 256, 768);
    launch_gemm(ABF, WT, taste_b, xs[2], nullptr, nullptr, M, 256, 768, nullptr, 0, 0, 0, stream);
    // intent (K=20 -> pad 32)
    conv_pad<<<(M * 32 + 255) / 256, 256, 0, stream>>>(intent_feat, ABF, M, 20, 32);
    wtconv<<<(256 * 32 + 255) / 256, 256, 0, stream>>>(intent_W, WT, 20, 256, 32);
    launch_gemm(ABF, WT, intent_b, xs[3], nullptr, nullptr, M, 256, 32, nullptr, 0, 0, 0, stream);
    // image low-rank
    convf4<<<(15360000 / 4 + 255) / 256, 256, 0, stream>>>(image_feat, ABF, 15360000 / 4);
    wtconv<<<(64 * 512 + 255) / 256, 256, 0, stream>>>(img_U, WT, 512, 64, 512);
    launch_gemm(ABF, WT, nullptr, SCR, nullptr, nullptr, M, 64, 512, nullptr, 0, 0, 0, stream);
    convf4<<<(1920000 / 4 + 255) / 256, 256, 0, stream>>>(SCR, ABF + 16000000, 1920000 / 4);
    wtconv<<<(256 * 64 + 255) / 256, 256, 0, stream>>>(img_V, WT, 64, 256, 64);
    launch_gemm(ABF + 16000000, WT, img_b, xs[4], nullptr, nullptr, M, 256, 64, nullptr, 0, 0, 0, stream);
    // user
    convf4<<<(1920000 / 4 + 255) / 256, 256, 0, stream>>>(user_emb, ABF, 1920000 / 4);
    wtconv<<<(256 * 64 + 255) / 256, 256, 0, stream>>>(user_W, WT, 64, 256, 64);
    launch_gemm(ABF, WT, user_b, SCR, nullptr, nullptr, M, 256, 64, user_id, 0, 0, 0, stream);
    hipMemsetAsync(BNS, 0, 512 * 4, stream);
    bn_stats<<<120, 256, 0, stream>>>(SCR, BNS, M);
    bn_apply<<<2048, 256, 0, stream>>>(SCR, BNS, user_bn_g, user_bn_b, xs[0], M);
    // item
    convf4<<<(1920000 / 4 + 255) / 256, 256, 0, stream>>>(item_emb, ABF, 1920000 / 4);
    wtconv<<<(256 * 64 + 255) / 256, 256, 0, stream>>>(item_W, WT, 64, 256, 64);
    launch_gemm(ABF, WT, item_b, SCR, nullptr, nullptr, M, 256, 64, item_id, 0, 0, 0, stream);
    hipMemsetAsync(BNS, 0, 512 * 4, stream);
    bn_stats<<<120, 256, 0, stream>>>(SCR, BNS, M);
    bn_apply<<<2048, 256, 0, stream>>>(SCR, BNS, item_bn_g, item_bn_b, xs[1], M);

    // ---------------- layers ----------------
    static const int esrc[5] = {3, 4, 0, 1, 2};  // src type t -> edge index
    for (int l = 0; l < 2; ++l) {
        for (int t = 0; t < 5; ++t) {
            int e = esrc[t];
            convf4<<<(S / 4 + 255) / 256, 256, 0, stream>>>(xs[t], ABF, S / 4);
            int inclQ = (t < 2) ? 1 : 0;
            int ncols = inclQ ? 768 : 512;
            build_fusedT<<<(257 * ncols + 255) / 256, 256, 0, stream>>>(
                kqv_W + (size_t)(l * 5 + t) * 256 * 768, kqv_b + (size_t)(l * 5 + t) * 768,
                k_rel + (size_t)(l * 5 + e) * 4 * 64 * 64, v_rel + (size_t)(l * 5 + e) * 4 * 64 * 64,
                WT, bfv, inclQ);
            if (t < 2) {
                launch_gemm(ABF, WT, bfv, KE + t * S, Q + t * S, VEb + t * S,
                            M, 768, 256, nullptr, 1, 0, 0, stream);
            } else {
                launch_gemm(ABF, WT, bfv, SCR, nullptr, VEb + t * S,
                            M, 512, 256, nullptr, 3, 0, 0, stream);
                int blocks = (NNODE * 4 * 16 + 255) / 256;
                logit_assoc<<<blocks, 256, 0, stream>>>(Q + S, SCR, p_rel + (size_t)(l * 5 + e) * 4,
                                                        LI + (size_t)e * 120000);
            }
        }
        // dst = item
        {
            int blocks = (NNODE * 64 + 255) / 256;
            hipLaunchKernelGGL((attn_gather<1>), dim3(blocks), dim3(256), 0, stream,
                Q + S, KE, VEb, LI, VEb + 2 * S, off_i, eid_i, buys_src,
                p_rel + (size_t)(l * 5 + 3) * 4, ABF);
        }
        wtconv<<<(256 * 256 + 255) / 256, 256, 0, stream>>>(out_W + (size_t)(l * 5 + 1) * 65536, WT, 256, 256, 256);
        launch_gemm(ABF, WT, out_b + (size_t)(l * 5 + 1) * 256, SCR, nullptr, nullptr,
                    M, 256, 256, nullptr, 2, skip + (l * 5 + 1), xs[1], stream);
        hipMemsetAsync(BNS, 0, 512 * 4, stream);
        bn_stats<<<120, 256, 0, stream>>>(SCR, BNS, M);
        bn_apply<<<2048, 256, 0, stream>>>(SCR, BNS, fbn_g + (l * 2 + 1) * 256, fbn_b + (l * 2 + 1) * 256, xs[1], M);
        // dst = user
        {
            int blocks = (NNODE * 64 + 255) / 256;
            hipLaunchKernelGGL((attn_gather<0>), dim3(blocks), dim3(256), 0, stream,
                Q, KE + S, VEb + S, nullptr, nullptr, off_u, eid_u, buys_dst,
                p_rel + (size_t)(l * 5 + 4) * 4, ABF);
        }
        wtconv<<<(256 * 256 + 255) / 256, 256, 0, stream>>>(out_W + (size_t)(l * 5 + 0) * 65536, WT, 256, 256, 256);
        launch_gemm(ABF, WT, out_b + (size_t)(l * 5 + 0) * 256, SCR, nullptr, nullptr,
                    M, 256, 256, nullptr, 2, skip + (l * 5 + 0), xs[0], stream);
        hipMemsetAsync(BNS, 0, 512 * 4, stream);
        bn_stats<<<120, 256, 0, stream>>>(SCR, BNS, M);
        bn_apply<<<2048, 256, 0, stream>>>(SCR, BNS, fbn_g + (l * 2 + 0) * 256, fbn_b + (l * 2 + 0) * 256, xs[0], M);
    }
}